// Round 1
// baseline (487.067 us; speedup 1.0000x reference)
//
#include <hip/hip_runtime.h>
#include <stdint.h>
#include <stddef.h>

#define DI __device__ __forceinline__

typedef unsigned short u16;
typedef float f32x4 __attribute__((ext_vector_type(4)));
typedef short bf16x8 __attribute__((ext_vector_type(8)));
typedef u16 u16x4 __attribute__((ext_vector_type(4)));

// B=8, N=1024, D=1024, H=16, HD=64, M=8192
constexpr int Mm = 8192;
constexpr int Dd = 1024;

DI u16 f2bf(float f) {
  union { float f; unsigned int u; } v; v.f = f;
  unsigned int u = v.u;
  return (u16)((u + 0x7FFFu + ((u >> 16) & 1u)) >> 16);
}

DI f32x4 mfma16(bf16x8 a, bf16x8 b, f32x4 c) {
  return __builtin_amdgcn_mfma_f32_16x16x32_bf16(a, b, c, 0, 0, 0);
}

// ---------------- convert x (f32 -> bf16), 4 elems/thread ----------------
__global__ __launch_bounds__(256) void k_cvt(const float* __restrict__ x,
                                             u16* __restrict__ o) {
  size_t i = (size_t)blockIdx.x * 256 + threadIdx.x;
  float4 v = *(const float4*)(x + i * 4);
  u16x4 r;
  r.x = f2bf(v.x); r.y = f2bf(v.y); r.z = f2bf(v.z); r.w = f2bf(v.w);
  *(u16x4*)(o + i * 4) = r;
}

// ---------------- transpose 1024x1024 f32 W -> bf16 WT[n][k] ----------------
__global__ __launch_bounds__(256) void k_tr(const float* __restrict__ W,
                                            u16* __restrict__ WT) {
  __shared__ float t[32][33];
  int bx = blockIdx.x * 32;  // k block
  int by = blockIdx.y * 32;  // n block
  int tx = threadIdx.x, ty = threadIdx.y;  // (32,8)
#pragma unroll
  for (int i = 0; i < 4; ++i)
    t[ty + i * 8][tx] = W[(size_t)(bx + ty + i * 8) * 1024 + by + tx];
  __syncthreads();
#pragma unroll
  for (int i = 0; i < 4; ++i)
    WT[(size_t)(by + ty + i * 8) * 1024 + bx + tx] = f2bf(t[tx][ty + i * 8]);
}

// ---------------- GEMM: C[M,1024] = A[M,1024](bf16) @ WT[1024,1024]^T ----------------
// MODE 0: Q  -> bf16 (acc+bias)*0.125, layout [m][d]
// MODE 1: K  -> bf16 acc+bias,          layout [m][d]
// MODE 2: V  -> bf16 acc+bias, transposed layout [b][d][seq]
// MODE 3: O  -> f32 acc+bias+resid,     layout [m][d]
template <int MODE>
__global__ __launch_bounds__(256) void k_gemm(const u16* __restrict__ A,
                                              const u16* __restrict__ WT,
                                              const float* __restrict__ bias,
                                              const float* __restrict__ resid,
                                              void* __restrict__ outp) {
  __shared__ __align__(16) u16 As[128 * 64];
  __shared__ __align__(16) u16 Bs[128 * 64];
  char* AsB = (char*)As;
  char* BsB = (char*)Bs;
  const int tid = threadIdx.x;
  const int lane = tid & 63;
  const int wave = tid >> 6;
  const int brow = blockIdx.y * 128;
  const int bcol = blockIdx.x * 128;
  const int wr = (wave >> 1) * 64;
  const int wc = (wave & 1) * 64;
  const int l15 = lane & 15, l4 = lane >> 4;

  f32x4 acc[4][4] = {};

  bf16x8 sga[4], sgb[4];
  int srow[4], spos[4];
#pragma unroll
  for (int r = 0; r < 4; ++r) {
    int chunk = r * 256 + tid;   // 1024 chunks of 16B = 128 rows x 8 chunks
    srow[r] = chunk >> 3;
    spos[r] = chunk & 7;
  }

#pragma unroll
  for (int r = 0; r < 4; ++r) {  // prefetch tile 0
    sga[r] = *(const bf16x8*)(A + (size_t)(brow + srow[r]) * 1024 + spos[r] * 8);
    sgb[r] = *(const bf16x8*)(WT + (size_t)(bcol + srow[r]) * 1024 + spos[r] * 8);
  }

  for (int t = 0; t < 16; ++t) {
    // write staged tile to LDS (XOR-swizzled rows: byte ^= (row&7)<<4)
#pragma unroll
    for (int r = 0; r < 4; ++r) {
      int off = srow[r] * 128 + ((spos[r] * 16) ^ ((srow[r] & 7) << 4));
      *(bf16x8*)(AsB + off) = sga[r];
      *(bf16x8*)(BsB + off) = sgb[r];
    }
    __syncthreads();
    if (t < 15) {
      int k0 = (t + 1) * 64;
#pragma unroll
      for (int r = 0; r < 4; ++r) {
        sga[r] = *(const bf16x8*)(A + (size_t)(brow + srow[r]) * 1024 + k0 + spos[r] * 8);
        sgb[r] = *(const bf16x8*)(WT + (size_t)(bcol + srow[r]) * 1024 + k0 + spos[r] * 8);
      }
    }
#pragma unroll
    for (int kk = 0; kk < 2; ++kk) {
      bf16x8 af[4], bf_[4];
      int kb = kk * 64 + l4 * 16;
#pragma unroll
      for (int mt = 0; mt < 4; ++mt) {
        int row = wr + mt * 16 + l15;
        af[mt] = *(const bf16x8*)(AsB + row * 128 + (kb ^ ((row & 7) << 4)));
      }
#pragma unroll
      for (int nt = 0; nt < 4; ++nt) {
        int row = wc + nt * 16 + l15;
        bf_[nt] = *(const bf16x8*)(BsB + row * 128 + (kb ^ ((row & 7) << 4)));
      }
#pragma unroll
      for (int mt = 0; mt < 4; ++mt)
#pragma unroll
        for (int nt = 0; nt < 4; ++nt)
          acc[mt][nt] = mfma16(af[mt], bf_[nt], acc[mt][nt]);
    }
    __syncthreads();
  }

  // epilogue. C/D: col = lane&15, row = (lane>>4)*4 + i
#pragma unroll
  for (int nt = 0; nt < 4; ++nt) {
    int gc = bcol + wc + nt * 16 + l15;
    float bv = bias[gc];
#pragma unroll
    for (int mt = 0; mt < 4; ++mt) {
#pragma unroll
      for (int i = 0; i < 4; ++i) {
        int gm = brow + wr + mt * 16 + l4 * 4 + i;
        float v = acc[mt][nt][i] + bv;
        if (MODE == 0) {
          ((u16*)outp)[(size_t)gm * 1024 + gc] = f2bf(v * 0.125f);
        } else if (MODE == 1) {
          ((u16*)outp)[(size_t)gm * 1024 + gc] = f2bf(v);
        } else if (MODE == 2) {
          ((u16*)outp)[((size_t)(gm >> 10) * 1024 + gc) * 1024 + (gm & 1023)] = f2bf(v);
        } else {
          ((float*)outp)[(size_t)gm * 1024 + gc] = v + resid[(size_t)gm * 1024 + gc];
        }
      }
    }
  }
}

// ---------------- attention: per (b,h), 16 q-rows per block ----------------
// q [m][d] bf16 (pre-scaled 1/8), k [m][d] bf16, vt [b][d][seq] bf16
// attn_out [b*h][n][n] f32, aout [m][d] bf16
__global__ __launch_bounds__(256) void k_attn(const u16* __restrict__ q,
                                              const u16* __restrict__ kk_,
                                              const u16* __restrict__ vt,
                                              const float* __restrict__ pb,
                                              float* __restrict__ attn_out,
                                              u16* __restrict__ aout) {
  __shared__ __align__(16) float sc[16 * 1024];  // 64 KB
  const int tid = threadIdx.x;
  const int lane = tid & 63;
  const int wave = tid >> 6;
  const int q0 = blockIdx.x * 16;
  const int bh = blockIdx.y;
  const int b = bh >> 4, h = bh & 15;
  const int l15 = lane & 15, l4 = lane >> 4;

  // ---- scores = Q K^T + pair_bias, into swizzled LDS ----
  bf16x8 aq0, aq1;
  {
    const u16* qp = q + ((size_t)(b * 1024 + q0 + l15)) * 1024 + h * 64 + l4 * 8;
    aq0 = *(const bf16x8*)qp;
    aq1 = *(const bf16x8*)(qp + 32);
  }
  const int colbase = wave * 256;
#pragma unroll 4
  for (int nt = 0; nt < 16; ++nt) {
    int col = colbase + nt * 16 + l15;
    const u16* kp = kk_ + ((size_t)(b * 1024 + col)) * 1024 + h * 64 + l4 * 8;
    bf16x8 b0 = *(const bf16x8*)kp;
    bf16x8 b1 = *(const bf16x8*)(kp + 32);
    f32x4 c = {};
    c = mfma16(aq0, b0, c);
    c = mfma16(aq1, b1, c);
#pragma unroll
    for (int i = 0; i < 4; ++i) {
      int r = l4 * 4 + i;
      float v = c[i] + pb[(size_t)(q0 + r) * 1024 + col];
      sc[r * 1024 + (col ^ ((r & 7) << 3))] = v;
    }
  }
  __syncthreads();

  // ---- softmax: 16 threads per row (contiguous lanes) ----
  {
    int r = tid >> 4;
    int l = tid & 15;
    int rx = (r & 7) << 3;
    float mx = -3e38f;
#pragma unroll 4
    for (int i = 0; i < 16; ++i) {
      int c0 = (i * 16 + l) * 4;
      float4 v = *(const float4*)&sc[r * 1024 + (c0 ^ rx)];
      mx = fmaxf(mx, fmaxf(fmaxf(v.x, v.y), fmaxf(v.z, v.w)));
    }
#pragma unroll
    for (int o = 1; o < 16; o <<= 1) mx = fmaxf(mx, __shfl_xor(mx, o));
    float sum = 0.f;
#pragma unroll 4
    for (int i = 0; i < 16; ++i) {
      int c0 = (i * 16 + l) * 4;
      float4* p = (float4*)&sc[r * 1024 + (c0 ^ rx)];
      float4 v = *p;
      v.x = __expf(v.x - mx); v.y = __expf(v.y - mx);
      v.z = __expf(v.z - mx); v.w = __expf(v.w - mx);
      *p = v;
      sum += v.x + v.y + v.z + v.w;
    }
#pragma unroll
    for (int o = 1; o < 16; o <<= 1) sum += __shfl_xor(sum, o);
    float inv = 1.f / sum;
    float* gout = attn_out + ((size_t)bh * 1024 + q0 + r) * 1024;
#pragma unroll 4
    for (int i = 0; i < 16; ++i) {
      int c0 = (i * 16 + l) * 4;
      float4* p = (float4*)&sc[r * 1024 + (c0 ^ rx)];
      float4 v = *p;
      v.x *= inv; v.y *= inv; v.z *= inv; v.w *= inv;
      *p = v;                       // normalized P kept for PV
      *(float4*)(gout + c0) = v;    // attn output (fp32, coalesced)
    }
  }
  __syncthreads();

  // ---- PV: each wave does kv range [wave*256, +256), k-split reduce ----
  f32x4 pacc[4] = {};
  const int kvw = wave * 256;
#pragma unroll 2
  for (int ks = 0; ks < 8; ++ks) {
    int r = l15;
    int c0 = kvw + ks * 32 + l4 * 8;
    int off = r * 1024 + (c0 ^ ((r & 7) << 3));
    float4 p0 = *(const float4*)&sc[off];
    float4 p1 = *(const float4*)&sc[off + 4];
    bf16x8 af;
    af[0] = (short)f2bf(p0.x); af[1] = (short)f2bf(p0.y);
    af[2] = (short)f2bf(p0.z); af[3] = (short)f2bf(p0.w);
    af[4] = (short)f2bf(p1.x); af[5] = (short)f2bf(p1.y);
    af[6] = (short)f2bf(p1.z); af[7] = (short)f2bf(p1.w);
#pragma unroll
    for (int nt = 0; nt < 4; ++nt) {
      const u16* vp = vt + ((size_t)b * 1024 + h * 64 + nt * 16 + l15) * 1024 + c0;
      bf16x8 bv = *(const bf16x8*)vp;
      pacc[nt] = mfma16(af, bv, pacc[nt]);
    }
  }
  __syncthreads();
#pragma unroll
  for (int nt = 0; nt < 4; ++nt)
#pragma unroll
    for (int i = 0; i < 4; ++i)
      sc[wave * 1024 + (l4 * 4 + i) * 64 + nt * 16 + l15] = pacc[nt][i];
  __syncthreads();
#pragma unroll
  for (int it = 0; it < 4; ++it) {
    int o = it * 256 + tid;
    int r = o >> 6, c = o & 63;
    float s = sc[o] + sc[1024 + o] + sc[2048 + o] + sc[3072 + o];
    aout[(size_t)(b * 1024 + q0 + r) * 1024 + h * 64 + c] = f2bf(s);
  }
}

// ---------------- LayerNorm: one wave per row ----------------
__global__ __launch_bounds__(256) void k_ln(const float* __restrict__ y,
                                            const float* __restrict__ g,
                                            const float* __restrict__ be,
                                            float* __restrict__ o) {
  const int lane = threadIdx.x & 63;
  const int wave = threadIdx.x >> 6;
  size_t row = (size_t)blockIdx.x * 4 + wave;
  const float* yr = y + row * 1024;
  float4 v[4];
  float s = 0.f, sq = 0.f;
#pragma unroll
  for (int i = 0; i < 4; ++i) {
    v[i] = *(const float4*)(yr + i * 256 + lane * 4);
    s += v[i].x + v[i].y + v[i].z + v[i].w;
    sq += v[i].x * v[i].x + v[i].y * v[i].y + v[i].z * v[i].z + v[i].w * v[i].w;
  }
#pragma unroll
  for (int off = 1; off < 64; off <<= 1) {
    s += __shfl_xor(s, off);
    sq += __shfl_xor(sq, off);
  }
  float mu = s * (1.f / 1024.f);
  float var = sq * (1.f / 1024.f) - mu * mu;
  float rs = rsqrtf(fmaxf(var, 0.f) + 1e-5f);
  float* orow = o + row * 1024;
#pragma unroll
  for (int i = 0; i < 4; ++i) {
    int c = i * 256 + lane * 4;
    float4 gg = *(const float4*)(g + c);
    float4 bb = *(const float4*)(be + c);
    float4 r;
    r.x = (v[i].x - mu) * rs * gg.x + bb.x;
    r.y = (v[i].y - mu) * rs * gg.y + bb.y;
    r.z = (v[i].z - mu) * rs * gg.z + bb.z;
    r.w = (v[i].w - mu) * rs * gg.w + bb.w;
    *(float4*)(orow + c) = r;
  }
}

extern "C" void kernel_launch(void* const* d_in, const int* in_sizes, int n_in,
                              void* d_out, int out_size, void* d_ws, size_t ws_size,
                              hipStream_t stream) {
  const float* x = (const float*)d_in[0];
  const float* Wq = (const float*)d_in[1];
  const float* bq = (const float*)d_in[2];
  const float* Wk = (const float*)d_in[3];
  const float* bk = (const float*)d_in[4];
  const float* Wv = (const float*)d_in[5];
  const float* bv = (const float*)d_in[6];
  const float* pb = (const float*)d_in[7];
  const float* Wo = (const float*)d_in[8];
  const float* bo = (const float*)d_in[9];
  const float* gamma = (const float*)d_in[10];
  const float* beta = (const float*)d_in[11];

  char* ws = (char*)d_ws;
  // layout (MB): [0,16) xb then aows (reuse; xb dead after V gemm)
  // [16,24) WT x4, [24,40) q, [40,56) k, [56,72) vt, [72,104) y (f32)
  u16* xb = (u16*)(ws);
  u16* aows = (u16*)(ws);
  u16* wqT = (u16*)(ws + (16u << 20));
  u16* wkT = (u16*)(ws + (18u << 20));
  u16* wvT = (u16*)(ws + (20u << 20));
  u16* woT = (u16*)(ws + (22u << 20));
  u16* qws = (u16*)(ws + (24u << 20));
  u16* kws = (u16*)(ws + (40u << 20));
  u16* vtws = (u16*)(ws + (56u << 20));
  float* yws = (float*)(ws + (72u << 20));

  float* out_ln = (float*)d_out;
  float* out_attn = out_ln + (size_t)Mm * Dd;

  k_cvt<<<8192, 256, 0, stream>>>(x, xb);
  k_tr<<<dim3(32, 32), dim3(32, 8), 0, stream>>>(Wq, wqT);
  k_tr<<<dim3(32, 32), dim3(32, 8), 0, stream>>>(Wk, wkT);
  k_tr<<<dim3(32, 32), dim3(32, 8), 0, stream>>>(Wv, wvT);
  k_tr<<<dim3(32, 32), dim3(32, 8), 0, stream>>>(Wo, woT);
  k_gemm<0><<<dim3(8, 64), 256, 0, stream>>>(xb, wqT, bq, nullptr, qws);
  k_gemm<1><<<dim3(8, 64), 256, 0, stream>>>(xb, wkT, bk, nullptr, kws);
  k_gemm<2><<<dim3(8, 64), 256, 0, stream>>>(xb, wvT, bv, nullptr, vtws);
  k_attn<<<dim3(64, 128), 256, 0, stream>>>(qws, kws, vtws, pb, out_attn, aows);
  k_gemm<3><<<dim3(8, 64), 256, 0, stream>>>(aows, woT, bo, x, yws);
  k_ln<<<2048, 256, 0, stream>>>(yws, gamma, beta, out_ln);
}